// Round 13
// baseline (250.675 us; speedup 1.0000x reference)
//
#include <hip/hip_runtime.h>
#include <hip/hip_cooperative_groups.h>
#include <float.h>

namespace cg = cooperative_groups;

#define BATCH 32
#define NP 512
#define NG 512
#define TSTEP 10
#define NI (NG * TSTEP)                   // 5120 candidates per batch
#define NCHUNK 16                         // chunks per batch
#define CH_CANDS (NI / NCHUNK)            // 320 cands per chunk
#define CH_PAIRS (CH_CANDS / 2)           // 160 float4 pairs per chunk
#define TILE_CANDS 16
#define TILE_PAIRS 8
#define TILES_CH (CH_PAIRS / TILE_PAIRS)  // 20 tiles per chunk
#define NB_SCAN (BATCH * NCHUNK)          // 512
#define NB_G2P 64                         // 2 blocks/batch, 256 gt pts each
#define NB_ALL (NB_SCAN + NB_G2P)         // 576 blocks — all co-resident (2.25/CU)
#define THR 256
#define RPT 2                             // preds per thread (RPT*256 = NP)
#define NPRED (BATCH * NP)                // 16384

typedef float f2 __attribute__((ext_vector_type(2)));

__device__ __forceinline__ float wave_reduce(float v) {
#pragma unroll
    for (int o = 32; o > 0; o >>= 1) v += __shfl_down(v, o);
    return v;
}

__device__ __forceinline__ unsigned long long aload64(const unsigned long long* p) {
    return __hip_atomic_load(p, __ATOMIC_RELAXED, __HIP_MEMORY_SCOPE_AGENT);
}
__device__ __forceinline__ float aloadf(const float* p) {
    return __hip_atomic_load(p, __ATOMIC_RELAXED, __HIP_MEMORY_SCOPE_AGENT);
}

// =================== single cooperative kernel ===================
// Phase 1: blocks [0,512) = (batch,chunk) scan (r6 body); blocks [512,576) = g2p (r6 body).
// grid.sync()
// Phase 2: blocks [0,64) = fold 16 chunk packs + rescan winning tile + L1 reduce (r6 k_comb).
// grid.sync()
// Phase 3: block 0 = final scalar (r6 k_final).
__global__ __launch_bounds__(THR) void k_all(
    const float* __restrict__ gt, const float* __restrict__ pred0,
    const float* __restrict__ pred1, const float* __restrict__ mask,
    unsigned long long* __restrict__ packs, float* __restrict__ psum,
    float* __restrict__ gsum, float* __restrict__ msum, float* __restrict__ out) {
    __shared__ float2 sTFU[TSTEP];      // (tf, 1-tf) interp weights
    __shared__ float4 sC4[CH_PAIRS];    // chunk candidates, pair layout (x0,x1,y0,y1)
    __shared__ float2 sP[NP];           // g2p pred stage
    __shared__ float swl[4], swm[4];
    const int bid = blockIdx.x, tid = threadIdx.x;
    cg::grid_group grid = cg::this_grid();

    // ---------------- phase 1 ----------------
    if (bid < NB_SCAN) {
        const int b = bid >> 4, ch = bid & (NCHUNK - 1);
        const float* gtb = gt + b * NG * 2;
        if (tid < TSTEP) {
            float tf = (float)tid / 10.0f;           // same expr as rounds 1-12
            sTFU[tid] = make_float2(tf, 1.0f - tf);
        }
        __syncthreads();
        if (tid < CH_PAIRS) {   // stage one pair/thread — bitwise-identical to r6
            int k0 = ch * CH_CANDS + 2 * tid, k1 = k0 + 1;
            int j0 = k0 / TSTEP, t0 = k0 - j0 * TSTEP;
            int j1 = k1 / TSTEP, t1 = k1 - j1 * TSTEP;
            int jm0 = (j0 + NG - 1) & (NG - 1), jm1 = (j1 + NG - 1) & (NG - 1);
            float2 w0 = sTFU[t0], w1 = sTFU[t1];
            float x0 = fmaf(gtb[2 * j0], w0.x, gtb[2 * jm0] * w0.y);
            float y0 = fmaf(gtb[2 * j0 + 1], w0.x, gtb[2 * jm0 + 1] * w0.y);
            float x1 = fmaf(gtb[2 * j1], w1.x, gtb[2 * jm1] * w1.y);
            float y1 = fmaf(gtb[2 * j1 + 1], w1.x, gtb[2 * jm1 + 1] * w1.y);
            sC4[tid] = make_float4(x0, x1, y0, y1);
        }
        f2 PX[RPT], PY[RPT];
#pragma unroll
        for (int r = 0; r < RPT; ++r) {
            const float2 p = *(const float2*)(pred0 + (b * NP + r * THR + tid) * 2);
            PX[r] = (f2){p.x, p.x};
            PY[r] = (f2){p.y, p.y};
        }
        __syncthreads();

        float best[RPT] = {FLT_MAX, FLT_MAX};
        int btile[RPT] = {0, 0};
#pragma unroll 1
        for (int t = 0; t < TILES_CH; ++t) {
            float acc[RPT] = {FLT_MAX, FLT_MAX};
#pragma unroll
            for (int q = 0; q < TILE_PAIRS; ++q) {
                const float4 c = sC4[t * TILE_PAIRS + q];   // uniform broadcast read
                const f2 cx = {c.x, c.y}, cy = {c.z, c.w};
#pragma unroll
                for (int r = 0; r < RPT; ++r) {
                    f2 dx = cx - PX[r], dy = cy - PY[r];
                    f2 d = __builtin_elementwise_fma(dy, dy, dx * dx);
                    acc[r] = fminf(fminf(d.x, d.y), acc[r]);   // v_min3
                }
            }
            const int tg = ch * TILES_CH + t;   // global tile id, ascending with chunk
#pragma unroll
            for (int r = 0; r < RPT; ++r)
                if (acc[r] < best[r]) { best[r] = acc[r]; btile[r] = tg; }  // strict <
        }
        // dist>=0 -> bits monotone; tile in low bits -> u64 min = exact first-min tile.
#pragma unroll
        for (int r = 0; r < RPT; ++r)
            packs[(size_t)ch * NPRED + b * NP + r * THR + tid] =
                ((unsigned long long)__float_as_uint(best[r]) << 32) | (unsigned)btile[r];
    } else {
        // ------------- g2p: gt -> nearest pred (r6-proven body) -------------
        const int gb = bid - NB_SCAN;        // 0..63
        const int b = gb >> 1, gh = gb & 1;
        for (int k = tid; k < NP; k += THR)
            sP[k] = make_float2(pred0[(b * NP + k) * 2], pred0[(b * NP + k) * 2 + 1]);
        __syncthreads();

        const int g = gh * 256 + tid;
        const float gx = gt[(b * NG + g) * 2], gy = gt[(b * NG + g) * 2 + 1];
        float b0 = FLT_MAX, b1 = FLT_MAX;
        int i0 = 0, i1 = 0;
        const float4* s4 = (const float4*)sP;
#pragma unroll 4
        for (int i = 0; i < NP / 2; ++i) {
            float4 c = s4[i];
            float dx, dy, d;
            dx = gx - c.x; dy = gy - c.y; d = dx * dx + dy * dy;
            if (d < b0) { b0 = d; i0 = 2 * i; }
            dx = gx - c.z; dy = gy - c.w; d = dx * dx + dy * dy;
            if (d < b1) { b1 = d; i1 = 2 * i + 1; }
        }
        unsigned long long p0 = ((unsigned long long)__float_as_uint(b0) << 32) | (unsigned)i0;
        unsigned long long p1 = ((unsigned long long)__float_as_uint(b1) << 32) | (unsigned)i1;
        const int bi = (int)((p0 < p1 ? p0 : p1) & 0xFFFFFFFFull);
        const float m = mask[b * NG + g];
        float l = m * (fabsf(pred1[(b * NP + bi) * 2] - gx) +
                       fabsf(pred1[(b * NP + bi) * 2 + 1] - gy));
        float mm = 2.0f * m;
        l = wave_reduce(l);
        mm = wave_reduce(mm);
        if ((tid & 63) == 0) { swl[tid >> 6] = l; swm[tid >> 6] = mm; }
        __syncthreads();
        if (tid == 0) {
            gsum[gb] = swl[0] + swl[1] + swl[2] + swl[3];
            msum[gb] = swm[0] + swm[1] + swm[2] + swm[3];
        }
    }

    __threadfence();   // device-scope release of packs/gsum/msum
    grid.sync();

    // ---------------- phase 2: fold + rescan + L1 reduce (blocks 0..63) ----------------
    if (bid < 64) {
        const int pr = bid * THR + tid;      // one pred per thread
        const int b = pr >> 9;
        const float* gtb = gt + b * NG * 2;

        unsigned long long bp = aload64(&packs[pr]);
#pragma unroll
        for (int c = 1; c < NCHUNK; ++c) {
            unsigned long long v = aload64(&packs[(size_t)c * NPRED + pr]);
            if (v < bp) bp = v;
        }
        const float bestd = __uint_as_float((unsigned)(bp >> 32));
        const int wt = (int)(bp & 0xFFFFFFFFull);

        const float2 p = *(const float2*)(pred0 + pr * 2);
        const f2 pxx = {p.x, p.x}, pyy = {p.y, p.y};
        float nx = 0.f, ny = 0.f;
        bool found = false;
#pragma unroll
        for (int q = 0; q < TILE_PAIRS; ++q) {   // bitwise-identical recompute (r6-proven)
            int k0 = wt * TILE_CANDS + 2 * q, k1 = k0 + 1;
            int j0 = k0 / TSTEP, t0 = k0 - j0 * TSTEP;
            int j1 = k1 / TSTEP, t1 = k1 - j1 * TSTEP;
            int jm0 = (j0 + NG - 1) & (NG - 1), jm1 = (j1 + NG - 1) & (NG - 1);
            float tf0 = (float)t0 / 10.0f, uf0 = 1.0f - tf0;   // same bits as sTFU table
            float tf1 = (float)t1 / 10.0f, uf1 = 1.0f - tf1;
            float x0 = fmaf(gtb[2 * j0], tf0, gtb[2 * jm0] * uf0);
            float y0 = fmaf(gtb[2 * j0 + 1], tf0, gtb[2 * jm0 + 1] * uf0);
            float x1 = fmaf(gtb[2 * j1], tf1, gtb[2 * jm1] * uf1);
            float y1 = fmaf(gtb[2 * j1 + 1], tf1, gtb[2 * jm1 + 1] * uf1);
            f2 cx = {x0, x1}, cy = {y0, y1};
            f2 dx = cx - pxx, dy = cy - pyy;
            f2 d = __builtin_elementwise_fma(dy, dy, dx * dx);
            bool m0 = (d.x == bestd) && !found;
            nx = m0 ? x0 : nx; ny = m0 ? y0 : ny; found = found || m0;
            bool m1 = (d.y == bestd) && !found;
            nx = m1 ? x1 : nx; ny = m1 ? y1 : ny; found = found || m1;
        }
        float s = fabsf(pred1[pr * 2] - nx) + fabsf(pred1[pr * 2 + 1] - ny);
        s = wave_reduce(s);
        if ((tid & 63) == 0) swl[tid >> 6] = s;
        __syncthreads();
        if (tid == 0) psum[bid] = swl[0] + swl[1] + swl[2] + swl[3];
    }

    __threadfence();   // device-scope release of psum
    grid.sync();

    // ---------------- phase 3: final scalar (block 0; fixed order -> deterministic) ----
    if (bid == 0 && tid < 64) {
        float a = aloadf(&psum[tid]);
        float l = aloadf(&gsum[tid]);
        float m = aloadf(&msum[tid]);
        a = wave_reduce(a);
        l = wave_reduce(l);
        m = wave_reduce(m);
        if (tid == 0)
            out[0] = (l / (m + 1.0f) + a / (float)(NPRED * 2)) * 0.5f;
    }
}

extern "C" void kernel_launch(void* const* d_in, const int* in_sizes, int n_in,
                              void* d_out, int out_size, void* d_ws, size_t ws_size,
                              hipStream_t stream) {
    const float* pred0 = (const float*)d_in[0];   // ini_pred_poly [B,NP,2]
    const float* pred1 = (const float*)d_in[1];   // pred_polys_   [B,NP,2]
    const float* gt    = (const float*)d_in[2];   // gt_polys      [B,NG,2]
    const float* mask  = (const float*)d_in[3];   // keyPointsMask [B,NG]
    float* out = (float*)d_out;

    char* ws = (char*)d_ws;
    unsigned long long* packs = (unsigned long long*)ws;          // 16*16384*8 = 2 MB
    float* psum = (float*)(ws + (size_t)NCHUNK * NPRED * 8);      // 64
    float* gsum = psum + 64;                                      // 64
    float* msum = gsum + 64;                                      // 64

    void* args[] = {(void*)&gt, (void*)&pred0, (void*)&pred1, (void*)&mask,
                    (void*)&packs, (void*)&psum, (void*)&gsum, (void*)&msum, (void*)&out};
    hipLaunchCooperativeKernel((const void*)k_all, dim3(NB_ALL), dim3(THR),
                               args, 0, stream);
}

// Round 14
// 31.832 us; speedup vs baseline: 7.8749x; 7.8749x over previous
//
#include <hip/hip_runtime.h>
#include <float.h>

#define BATCH 32
#define NP 512
#define NG 512
#define TSTEP 10
#define NI (NG * TSTEP)                   // 5120 candidates per batch
#define NCHUNK 16                         // chunks per batch
#define CH_CANDS (NI / NCHUNK)            // 320 cands per chunk
#define CH_PAIRS (CH_CANDS / 2)           // 160 float4 pairs per chunk
#define TILE_CANDS 16
#define TILE_PAIRS 8
#define TILES_CH (CH_PAIRS / TILE_PAIRS)  // 20 tiles per chunk
#define NB_SCAN (BATCH * NCHUNK)          // 512
#define NB_G2P 64                         // 2 blocks/batch, 256 gt pts each
#define THR 256
#define RPT 2                             // preds per thread (RPT*256 = NP)
#define NPRED (BATCH * NP)                // 16384
#define NB_COMB 64                        // k_comb blocks (256 thr, 1 pred/thread)

typedef float f2 __attribute__((ext_vector_type(2)));

__device__ __forceinline__ float wave_reduce(float v) {
#pragma unroll
    for (int o = 32; o > 0; o >>= 1) v += __shfl_down(v, o);
    return v;
}

// =================== K_A: scan (chunk minima, plain stores) + g2p ===================
// EXACTLY round-6's champion kernel body (30.7 µs config), plus a one-thread
// counter re-arm for K_B (r7-proven cross-kernel-boundary init).
__global__ __launch_bounds__(THR) void k_scan(
    const float* __restrict__ gt, const float* __restrict__ pred0,
    const float* __restrict__ pred1, const float* __restrict__ mask,
    unsigned long long* __restrict__ packs,
    float* __restrict__ gsum, float* __restrict__ msum,
    unsigned int* __restrict__ counter) {
    __shared__ float2 sTFU[TSTEP];      // (tf, 1-tf) interp weights
    __shared__ float4 sC4[CH_PAIRS];    // chunk candidates, pair layout (x0,x1,y0,y1)
    __shared__ float2 sP[NP];           // g2p pred stage
    __shared__ float swl[4], swm[4];
    const int bid = blockIdx.x, tid = threadIdx.x;
    if (bid == NB_SCAN && tid == 0) *counter = 0u;   // visible to K_B at kernel boundary

    if (bid < NB_SCAN) {
        const int b = bid >> 4, ch = bid & (NCHUNK - 1);
        const float* gtb = gt + b * NG * 2;
        if (tid < TSTEP) {
            float tf = (float)tid / 10.0f;           // same expr as rounds 1-13
            sTFU[tid] = make_float2(tf, 1.0f - tf);
        }
        __syncthreads();
        if (tid < CH_PAIRS) {   // stage one pair/thread — bitwise-identical to r6
            int k0 = ch * CH_CANDS + 2 * tid, k1 = k0 + 1;
            int j0 = k0 / TSTEP, t0 = k0 - j0 * TSTEP;
            int j1 = k1 / TSTEP, t1 = k1 - j1 * TSTEP;
            int jm0 = (j0 + NG - 1) & (NG - 1), jm1 = (j1 + NG - 1) & (NG - 1);
            float2 w0 = sTFU[t0], w1 = sTFU[t1];
            float x0 = fmaf(gtb[2 * j0], w0.x, gtb[2 * jm0] * w0.y);
            float y0 = fmaf(gtb[2 * j0 + 1], w0.x, gtb[2 * jm0 + 1] * w0.y);
            float x1 = fmaf(gtb[2 * j1], w1.x, gtb[2 * jm1] * w1.y);
            float y1 = fmaf(gtb[2 * j1 + 1], w1.x, gtb[2 * jm1 + 1] * w1.y);
            sC4[tid] = make_float4(x0, x1, y0, y1);
        }
        f2 PX[RPT], PY[RPT];
#pragma unroll
        for (int r = 0; r < RPT; ++r) {
            const float2 p = *(const float2*)(pred0 + (b * NP + r * THR + tid) * 2);
            PX[r] = (f2){p.x, p.x};
            PY[r] = (f2){p.y, p.y};
        }
        __syncthreads();

        float best[RPT] = {FLT_MAX, FLT_MAX};
        int btile[RPT] = {0, 0};
#pragma unroll 1
        for (int t = 0; t < TILES_CH; ++t) {
            float acc[RPT] = {FLT_MAX, FLT_MAX};
#pragma unroll
            for (int q = 0; q < TILE_PAIRS; ++q) {
                const float4 c = sC4[t * TILE_PAIRS + q];   // uniform broadcast read
                const f2 cx = {c.x, c.y}, cy = {c.z, c.w};
#pragma unroll
                for (int r = 0; r < RPT; ++r) {
                    f2 dx = cx - PX[r], dy = cy - PY[r];
                    f2 d = __builtin_elementwise_fma(dy, dy, dx * dx);
                    acc[r] = fminf(fminf(d.x, d.y), acc[r]);   // v_min3
                }
            }
            const int tg = ch * TILES_CH + t;   // global tile id, ascending with chunk
#pragma unroll
            for (int r = 0; r < RPT; ++r)
                if (acc[r] < best[r]) { best[r] = acc[r]; btile[r] = tg; }  // strict <
        }
        // dist>=0 -> bits monotone; tile in low bits -> u64 min = exact first-min tile.
#pragma unroll
        for (int r = 0; r < RPT; ++r)
            packs[(size_t)ch * NPRED + b * NP + r * THR + tid] =
                ((unsigned long long)__float_as_uint(best[r]) << 32) | (unsigned)btile[r];
    } else {
        // ---------------- g2p: gt -> nearest pred (round-6-proven body) ----------------
        const int gb = bid - NB_SCAN;        // 0..63
        const int b = gb >> 1, gh = gb & 1;
        for (int k = tid; k < NP; k += THR)
            sP[k] = make_float2(pred0[(b * NP + k) * 2], pred0[(b * NP + k) * 2 + 1]);
        __syncthreads();

        const int g = gh * 256 + tid;
        const float gx = gt[(b * NG + g) * 2], gy = gt[(b * NG + g) * 2 + 1];
        float b0 = FLT_MAX, b1 = FLT_MAX;
        int i0 = 0, i1 = 0;
        const float4* s4 = (const float4*)sP;
#pragma unroll 4
        for (int i = 0; i < NP / 2; ++i) {
            float4 c = s4[i];
            float dx, dy, d;
            dx = gx - c.x; dy = gy - c.y; d = dx * dx + dy * dy;
            if (d < b0) { b0 = d; i0 = 2 * i; }
            dx = gx - c.z; dy = gy - c.w; d = dx * dx + dy * dy;
            if (d < b1) { b1 = d; i1 = 2 * i + 1; }
        }
        unsigned long long p0 = ((unsigned long long)__float_as_uint(b0) << 32) | (unsigned)i0;
        unsigned long long p1 = ((unsigned long long)__float_as_uint(b1) << 32) | (unsigned)i1;
        const int bi = (int)((p0 < p1 ? p0 : p1) & 0xFFFFFFFFull);
        const float m = mask[b * NG + g];
        float l = m * (fabsf(pred1[(b * NP + bi) * 2] - gx) +
                       fabsf(pred1[(b * NP + bi) * 2 + 1] - gy));
        float mm = 2.0f * m;
        l = wave_reduce(l);
        mm = wave_reduce(mm);
        if ((tid & 63) == 0) { swl[tid >> 6] = l; swm[tid >> 6] = mm; }
        __syncthreads();
        if (tid == 0) {
            gsum[gb] = swl[0] + swl[1] + swl[2] + swl[3];
            msum[gb] = swm[0] + swm[1] + swm[2] + swm[3];
        }
    }
}

// =================== K_B: fold + rescan + reduce + (last block) final ===================
// Round-6's k_comb (64 blocks x 256 thr), with r7-proven last-arriver final
// replacing the separate k_final dispatch.
__global__ __launch_bounds__(THR) void k_comb(
    const float* __restrict__ gt, const float* __restrict__ pred0,
    const float* __restrict__ pred1, const unsigned long long* __restrict__ packs,
    const float* __restrict__ gsum, const float* __restrict__ msum,
    float* __restrict__ psum, unsigned int* __restrict__ counter,
    float* __restrict__ out) {
    __shared__ float2 sTFU[TSTEP];
    __shared__ float sw[4];
    __shared__ int sLast;
    const int tid = threadIdx.x;
    const int pr = blockIdx.x * THR + tid;
    const int b = pr >> 9;
    const float* gtb = gt + b * NG * 2;
    if (tid < TSTEP) {
        float tf = (float)tid / 10.0f;
        sTFU[tid] = make_float2(tf, 1.0f - tf);
    }
    __syncthreads();

    // u64-min fold over 16 chunk packs = exact global first-min (tile ids ordered)
    unsigned long long bp = packs[pr];
#pragma unroll
    for (int c = 1; c < NCHUNK; ++c) {
        unsigned long long v = packs[(size_t)c * NPRED + pr];
        if (v < bp) bp = v;
    }
    const float bestd = __uint_as_float((unsigned)(bp >> 32));
    const int wt = (int)(bp & 0xFFFFFFFFull);

    const float2 p = *(const float2*)(pred0 + pr * 2);
    const f2 pxx = {p.x, p.x}, pyy = {p.y, p.y};
    float nx = 0.f, ny = 0.f;
    bool found = false;
#pragma unroll
    for (int q = 0; q < TILE_PAIRS; ++q) {   // bitwise-identical recompute (r6-proven)
        int k0 = wt * TILE_CANDS + 2 * q, k1 = k0 + 1;
        int j0 = k0 / TSTEP, t0 = k0 - j0 * TSTEP;
        int j1 = k1 / TSTEP, t1 = k1 - j1 * TSTEP;
        int jm0 = (j0 + NG - 1) & (NG - 1), jm1 = (j1 + NG - 1) & (NG - 1);
        float2 w0 = sTFU[t0], w1 = sTFU[t1];
        float x0 = fmaf(gtb[2 * j0], w0.x, gtb[2 * jm0] * w0.y);
        float y0 = fmaf(gtb[2 * j0 + 1], w0.x, gtb[2 * jm0 + 1] * w0.y);
        float x1 = fmaf(gtb[2 * j1], w1.x, gtb[2 * jm1] * w1.y);
        float y1 = fmaf(gtb[2 * j1 + 1], w1.x, gtb[2 * jm1 + 1] * w1.y);
        f2 cx = {x0, x1}, cy = {y0, y1};
        f2 dx = cx - pxx, dy = cy - pyy;
        f2 d = __builtin_elementwise_fma(dy, dy, dx * dx);
        bool m0 = (d.x == bestd) && !found;
        nx = m0 ? x0 : nx; ny = m0 ? y0 : ny; found = found || m0;
        bool m1 = (d.y == bestd) && !found;
        nx = m1 ? x1 : nx; ny = m1 ? y1 : ny; found = found || m1;
    }
    float s = fabsf(pred1[pr * 2] - nx) + fabsf(pred1[pr * 2 + 1] - ny);
    s = wave_reduce(s);
    if ((tid & 63) == 0) sw[tid >> 6] = s;
    __syncthreads();

    if (tid == 0) {
        __hip_atomic_store(&psum[blockIdx.x], sw[0] + sw[1] + sw[2] + sw[3],
                           __ATOMIC_RELAXED, __HIP_MEMORY_SCOPE_AGENT);
        unsigned tk = __hip_atomic_fetch_add(counter, 1u, __ATOMIC_ACQ_REL,
                                             __HIP_MEMORY_SCOPE_AGENT);
        sLast = (tk == NB_COMB - 1);
    }
    __syncthreads();
    if (!sLast || tid >= 64) return;

    // ---- final scalar (last block standing; fixed order -> deterministic) ----
    float a = __hip_atomic_load(&psum[tid], __ATOMIC_RELAXED, __HIP_MEMORY_SCOPE_AGENT);
    float l = gsum[tid];      // written by K_A (kernel-boundary visibility)
    float m = msum[tid];
    a = wave_reduce(a);
    l = wave_reduce(l);
    m = wave_reduce(m);
    if (tid == 0)
        out[0] = (l / (m + 1.0f) + a / (float)(NPRED * 2)) * 0.5f;
}

extern "C" void kernel_launch(void* const* d_in, const int* in_sizes, int n_in,
                              void* d_out, int out_size, void* d_ws, size_t ws_size,
                              hipStream_t stream) {
    const float* pred0 = (const float*)d_in[0];   // ini_pred_poly [B,NP,2]
    const float* pred1 = (const float*)d_in[1];   // pred_polys_   [B,NP,2]
    const float* gt    = (const float*)d_in[2];   // gt_polys      [B,NG,2]
    const float* mask  = (const float*)d_in[3];   // keyPointsMask [B,NG]
    float* out = (float*)d_out;

    char* ws = (char*)d_ws;
    unsigned long long* packs = (unsigned long long*)ws;          // 16*16384*8 = 2 MB
    float* psum = (float*)(ws + (size_t)NCHUNK * NPRED * 8);      // 64
    float* gsum = psum + NB_COMB;                                 // 64
    float* msum = gsum + NB_G2P;                                  // 64
    unsigned int* counter = (unsigned int*)(msum + NB_G2P);       // 1

    hipLaunchKernelGGL(k_scan, dim3(NB_SCAN + NB_G2P), dim3(THR), 0, stream,
                       gt, pred0, pred1, mask, packs, gsum, msum, counter);
    hipLaunchKernelGGL(k_comb, dim3(NB_COMB), dim3(THR), 0, stream,
                       gt, pred0, pred1, packs, gsum, msum, psum, counter, out);
}